// Round 13
// baseline (91.336 us; speedup 1.0000x reference)
//
#include <hip/hip_runtime.h>
#include <math.h>

// SPDNet fused, one wave per sample, no LDS, no scratch:
//  phase 1: Craw quadrants = sum_t x_t x_t^T via MFMA, x packed single-bf16,
//           lane = channel -> dwordx4 NONTEMPORAL loads along t (L1 bypass;
//           zero-reuse stream). 4-slot depth-3 software pipeline (R8-proven).
//  cov:     Cov = Craw/256 - mx mx^T (in-place on C-layout regs)
//  sandwich: Z = Cov*W ; Y = Z^T*W   (bf16 hi/lo rn-split, 3-product MFMA)
//  phase 2: log(Y) via degree-9 Chebyshev on [0.25,2.25] (p=1.25,q=1,r=-0.5)
//  epilogue: logits = <Wc_o, log(Y)> + bc -> log_softmax -> out.

typedef __attribute__((ext_vector_type(4))) float f32x4;    // NT-loadable
typedef __attribute__((ext_vector_type(8))) short short8;   // bf16x8 frag
typedef __attribute__((ext_vector_type(16))) float f32x16;  // MFMA C/D

#define NCH 9

__device__ inline unsigned cvt_pk_bf16(float a, float b) {
  unsigned r;
  asm("v_cvt_pk_bf16_f32 %0, %1, %2" : "=v"(r) : "v"(a), "v"(b));
  return r;
}
__device__ inline void split_pair(float a, float b, unsigned& hp, unsigned& lp) {
  hp = cvt_pk_bf16(a, b);
  const float ha = __builtin_bit_cast(float, hp << 16);
  const float hb = __builtin_bit_cast(float, hp & 0xffff0000u);
  lp = cvt_pk_bf16(a - ha, b - hb);
}
// two f32x4 (8 consecutive k) -> single rn-bf16 frag
__device__ inline short8 pack8f(const f32x4& u, const f32x4& v) {
  union { unsigned u4[4]; short8 s; } H;
  H.u4[0] = cvt_pk_bf16(u[0], u[1]);
  H.u4[1] = cvt_pk_bf16(u[2], u[3]);
  H.u4[2] = cvt_pk_bf16(v[0], v[1]);
  H.u4[3] = cvt_pk_bf16(v[2], v[3]);
  return H.s;
}

// C-layout (lane: col=l&31, rows (m&3)+8*(m>>2)+4*(l>>5)) of matrix M ->
// frag pairs for two K=16 slices, hi/lo split. As A-operand == M^T (== M when
// M symmetric), as B-operand == M.
__device__ inline void c2frags(const float* c, short8& h0, short8& l0,
                               short8& h1, short8& l1) {
  unsigned ph[8], pl[8];
#pragma unroll
  for (int w = 0; w < 8; ++w) split_pair(c[2 * w], c[2 * w + 1], ph[w], pl[w]);
  union { unsigned u[4]; short8 s; } H0, L0, H1, L1;
  auto r = __builtin_amdgcn_permlane32_swap((int)ph[0], (int)ph[2], false, false);
  H0.u[0] = (unsigned)r[0]; H0.u[2] = (unsigned)r[1];
  r = __builtin_amdgcn_permlane32_swap((int)ph[1], (int)ph[3], false, false);
  H0.u[1] = (unsigned)r[0]; H0.u[3] = (unsigned)r[1];
  r = __builtin_amdgcn_permlane32_swap((int)ph[4], (int)ph[6], false, false);
  H1.u[0] = (unsigned)r[0]; H1.u[2] = (unsigned)r[1];
  r = __builtin_amdgcn_permlane32_swap((int)ph[5], (int)ph[7], false, false);
  H1.u[1] = (unsigned)r[0]; H1.u[3] = (unsigned)r[1];
  r = __builtin_amdgcn_permlane32_swap((int)pl[0], (int)pl[2], false, false);
  L0.u[0] = (unsigned)r[0]; L0.u[2] = (unsigned)r[1];
  r = __builtin_amdgcn_permlane32_swap((int)pl[1], (int)pl[3], false, false);
  L0.u[1] = (unsigned)r[0]; L0.u[3] = (unsigned)r[1];
  r = __builtin_amdgcn_permlane32_swap((int)pl[4], (int)pl[6], false, false);
  L1.u[0] = (unsigned)r[0]; L1.u[2] = (unsigned)r[1];
  r = __builtin_amdgcn_permlane32_swap((int)pl[5], (int)pl[7], false, false);
  L1.u[1] = (unsigned)r[0]; L1.u[3] = (unsigned)r[1];
  h0 = H0.s; l0 = L0.s; h1 = H1.s; l1 = L1.s;
}

__device__ inline f32x16 mfma_bf16(short8 a, short8 b, f32x16 c) {
  return __builtin_amdgcn_mfma_f32_32x32x16_bf16(a, b, c, 0, 0, 0);
}
__device__ inline f32x16 zero16() {
  f32x16 z;
#pragma unroll
  for (int i = 0; i < 16; ++i) z[i] = 0.f;
  return z;
}
// W B-frag for channel-slice cs (k = cs*16+8*half+j), hi/lo split
__device__ inline void loadWfrag(const float* __restrict__ W, int cs, int half,
                                 int col, short8& h, short8& l) {
  float wr[8];
#pragma unroll
  for (int j = 0; j < 8; ++j) wr[j] = W[(cs * 16 + 8 * half + j) * 32 + col];
  union { unsigned u4[4]; short8 s; } H, L;
#pragma unroll
  for (int w = 0; w < 4; ++w) split_pair(wr[2 * w], wr[2 * w + 1], H.u4[w], L.u4[w]);
  h = H.s; l = L.s;
}

__global__ __launch_bounds__(256) void spd_fused(
    const float* __restrict__ x, const float* __restrict__ W,
    const float* __restrict__ Wc, const float* __restrict__ bcv,
    float* __restrict__ out, int nB)
{
  const int wv = threadIdx.x >> 6;
  const int l  = threadIdx.x & 63;
  const int b  = blockIdx.x * 4 + wv;
  if (b >= nB) return;
  const int half = l >> 5, col = l & 31;

  // ---- phase 1: Craw quadrants, 3-deep NT load pipeline ----
  const float* xb = x + (size_t)b * (64 * 256);
  const float* r0 = xb + col * 256 + 8 * half;        // channel col
  const float* r1 = r0 + 32 * 256;                    // channel 32+col

  f32x16 C00 = zero16(), C01 = zero16(), C10 = zero16(), C11 = zero16();
  float macc0 = 0.f, macc1 = 0.f;

  f32x4 buf[4][8];

#define LOADTB(slot, tb)                                                   \
  {                                                                        \
    const float* pa = r0 + (tb) * 32;                                      \
    buf[slot][0] = __builtin_nontemporal_load((const f32x4*)(pa));         \
    buf[slot][1] = __builtin_nontemporal_load((const f32x4*)(pa + 4));     \
    buf[slot][2] = __builtin_nontemporal_load((const f32x4*)(pa + 16));    \
    buf[slot][3] = __builtin_nontemporal_load((const f32x4*)(pa + 20));    \
    const float* pb = r1 + (tb) * 32;                                      \
    buf[slot][4] = __builtin_nontemporal_load((const f32x4*)(pb));         \
    buf[slot][5] = __builtin_nontemporal_load((const f32x4*)(pb + 4));     \
    buf[slot][6] = __builtin_nontemporal_load((const f32x4*)(pb + 16));    \
    buf[slot][7] = __builtin_nontemporal_load((const f32x4*)(pb + 20));    \
  }

  LOADTB(0, 0) LOADTB(1, 1)

#pragma unroll
  for (int tb = 0; tb < 8; ++tb) {
    if (tb + 2 < 8) LOADTB((tb + 2) & 3, tb + 2)
    const int s = tb & 3;
    const f32x4 a0 = buf[s][0], a1 = buf[s][1], a2 = buf[s][2], a3 = buf[s][3];
    const f32x4 b0 = buf[s][4], b1 = buf[s][5], b2 = buf[s][6], b3 = buf[s][7];

    macc0 += (a0[0] + a0[1] + a0[2] + a0[3]) + (a1[0] + a1[1] + a1[2] + a1[3]) +
             (a2[0] + a2[1] + a2[2] + a2[3]) + (a3[0] + a3[1] + a3[2] + a3[3]);
    macc1 += (b0[0] + b0[1] + b0[2] + b0[3]) + (b1[0] + b1[1] + b1[2] + b1[3]) +
             (b2[0] + b2[1] + b2[2] + b2[3]) + (b3[0] + b3[1] + b3[2] + b3[3]);

    const short8 A0 = pack8f(a0, a1), A1 = pack8f(a2, a3);
    const short8 B0 = pack8f(b0, b1), B1 = pack8f(b2, b3);

    C00 = mfma_bf16(A0, A0, C00); C00 = mfma_bf16(A1, A1, C00);
    C01 = mfma_bf16(A0, B0, C01); C01 = mfma_bf16(A1, B1, C01);
    C10 = mfma_bf16(B0, A0, C10); C10 = mfma_bf16(B1, A1, C10);
    C11 = mfma_bf16(B0, B0, C11); C11 = mfma_bf16(B1, B1, C11);
  }
#undef LOADTB

  // ---- means + correction: Cov = Craw/256 - mx mx^T (in-place) ----
  macc0 += __shfl_xor(macc0, 32);
  macc1 += __shfl_xor(macc1, 32);
  const float mx0 = macc0 * (1.f / 256.f);   // channel col
  const float mx1 = macc1 * (1.f / 256.f);   // channel 32+col
#pragma unroll
  for (int m = 0; m < 16; ++m) {
    const int r = (m & 3) + 8 * (m >> 2) + 4 * half;
    const float mr0 = __shfl(mx0, r);
    const float mr1 = __shfl(mx1, r);
    C00[m] = C00[m] * (1.f / 256.f) - mr0 * mx0;
    C01[m] = C01[m] * (1.f / 256.f) - mr0 * mx1;
    C10[m] = C10[m] * (1.f / 256.f) - mr1 * mx0;
    C11[m] = C11[m] * (1.f / 256.f) - mr1 * mx1;
  }

  // ---- eager quadrant->frag conversion (frees each accumulator asap) ----
  short8 f00h0, f00l0, f00h1, f00l1;   // A -> C00 (sym)
  {
    float t[16];
#pragma unroll
    for (int m = 0; m < 16; ++m) t[m] = C00[m];
    c2frags(t, f00h0, f00l0, f00h1, f00l1);
  }
  short8 f01h0, f01l0, f01h1, f01l1;   // A -> C01^T = C10
  {
    float t[16];
#pragma unroll
    for (int m = 0; m < 16; ++m) t[m] = C01[m];
    c2frags(t, f01h0, f01l0, f01h1, f01l1);
  }
  short8 f10h0, f10l0, f10h1, f10l1;   // A -> C10^T = C01
  {
    float t[16];
#pragma unroll
    for (int m = 0; m < 16; ++m) t[m] = C10[m];
    c2frags(t, f10h0, f10l0, f10h1, f10l1);
  }
  short8 f11h0, f11l0, f11h1, f11l1;   // A -> C11 (sym)
  {
    float t[16];
#pragma unroll
    for (int m = 0; m < 16; ++m) t[m] = C11[m];
    c2frags(t, f11h0, f11l0, f11h1, f11l1);
  }

  // ---- sandwich: Z = Cov*W (Z0 rows 0-31, Z1 rows 32-63) ----
  f32x16 Z0 = zero16(), Z1 = zero16();
  {
    short8 wh0, wl0, wh1, wl1;
    loadWfrag(W, 0, half, col, wh0, wl0);
    loadWfrag(W, 1, half, col, wh1, wl1);
    Z0 = mfma_bf16(f00h0, wh0, Z0); Z0 = mfma_bf16(f00h0, wl0, Z0); Z0 = mfma_bf16(f00l0, wh0, Z0);
    Z0 = mfma_bf16(f00h1, wh1, Z0); Z0 = mfma_bf16(f00h1, wl1, Z0); Z0 = mfma_bf16(f00l1, wh1, Z0);
    Z1 = mfma_bf16(f01h0, wh0, Z1); Z1 = mfma_bf16(f01h0, wl0, Z1); Z1 = mfma_bf16(f01l0, wh0, Z1);
    Z1 = mfma_bf16(f01h1, wh1, Z1); Z1 = mfma_bf16(f01h1, wl1, Z1); Z1 = mfma_bf16(f01l1, wh1, Z1);
  }
  {
    short8 wh2, wl2, wh3, wl3;
    loadWfrag(W, 2, half, col, wh2, wl2);
    loadWfrag(W, 3, half, col, wh3, wl3);
    Z0 = mfma_bf16(f10h0, wh2, Z0); Z0 = mfma_bf16(f10h0, wl2, Z0); Z0 = mfma_bf16(f10l0, wh2, Z0);
    Z0 = mfma_bf16(f10h1, wh3, Z0); Z0 = mfma_bf16(f10h1, wl3, Z0); Z0 = mfma_bf16(f10l1, wh3, Z0);
    Z1 = mfma_bf16(f11h0, wh2, Z1); Z1 = mfma_bf16(f11h0, wl2, Z1); Z1 = mfma_bf16(f11l0, wh2, Z1);
    Z1 = mfma_bf16(f11h1, wh3, Z1); Z1 = mfma_bf16(f11h1, wl3, Z1); Z1 = mfma_bf16(f11l1, wh3, Z1);
  }

  // ---- Y = Z^T * W (K = 64 channel rows of Z) ----
  f32x16 Ya = zero16();
  {
    short8 zh0, zl0, zh1, zl1;     // A -> Z0^T
    {
      float t[16];
#pragma unroll
      for (int m = 0; m < 16; ++m) t[m] = Z0[m];
      c2frags(t, zh0, zl0, zh1, zl1);
    }
    short8 wh0, wl0, wh1, wl1;
    loadWfrag(W, 0, half, col, wh0, wl0);
    loadWfrag(W, 1, half, col, wh1, wl1);
    Ya = mfma_bf16(zh0, wh0, Ya); Ya = mfma_bf16(zh0, wl0, Ya); Ya = mfma_bf16(zl0, wh0, Ya);
    Ya = mfma_bf16(zh1, wh1, Ya); Ya = mfma_bf16(zh1, wl1, Ya); Ya = mfma_bf16(zl1, wh1, Ya);
  }
  {
    short8 zh0, zl0, zh1, zl1;     // A -> Z1^T
    {
      float t[16];
#pragma unroll
      for (int m = 0; m < 16; ++m) t[m] = Z1[m];
      c2frags(t, zh0, zl0, zh1, zl1);
    }
    short8 wh2, wl2, wh3, wl3;
    loadWfrag(W, 2, half, col, wh2, wl2);
    loadWfrag(W, 3, half, col, wh3, wl3);
    Ya = mfma_bf16(zh0, wh2, Ya); Ya = mfma_bf16(zh0, wl2, Ya); Ya = mfma_bf16(zl0, wh2, Ya);
    Ya = mfma_bf16(zh1, wh3, Ya); Ya = mfma_bf16(zh1, wl3, Ya); Ya = mfma_bf16(zl1, wh3, Ya);
  }

  // ---- phase 2: Chebyshev log on [0.25, 2.25]: p=1.25, q=1, r=-0.5, c0=0 ----
  float Tc[16], Tp[16], G[16];
#pragma unroll
  for (int m = 0; m < 16; ++m) {
    const int r = (m & 3) + 8 * (m >> 2) + 4 * half;
    const float dg = (r == col) ? 1.f : 0.f;
    const float yn = Ya[m] - 1.25f * dg;      // u = (Y - p I)/q, q=1
    Tc[m] = yn; Tp[m] = dg;
    G[m] = yn;                                 // c1 = -2r = 1, c0 = 0
  }
  short8 ah0, al0, ah1, al1;
  c2frags(Tc, ah0, al0, ah1, al1);             // A-frags of symmetric Yhat

  constexpr float CK[NCH + 1] = {
      0.f, 1.f, -0.25f, 0.083333336f, -0.03125f, 0.0125f, -0.0052083335f,
      0.0022321427f, -0.0009765625f, 0.00043402778f};
#pragma unroll
  for (int k = 2; k <= NCH; ++k) {
    short8 bh0, bl0, bh1, bl1;
    c2frags(Tc, bh0, bl0, bh1, bl1);
    f32x16 P1 = zero16(), P2 = zero16();
    P1 = mfma_bf16(ah0, bh0, P1); P1 = mfma_bf16(ah0, bl0, P1); P1 = mfma_bf16(al0, bh0, P1);
    P2 = mfma_bf16(ah1, bh1, P2); P2 = mfma_bf16(ah1, bl1, P2); P2 = mfma_bf16(al1, bh1, P2);
    const float ck = CK[k];
#pragma unroll
    for (int m = 0; m < 16; ++m) {
      const float tn = 2.f * (P1[m] + P2[m]) - Tp[m];
      Tp[m] = Tc[m]; Tc[m] = tn;
      G[m] = fmaf(ck, tn, G[m]);
    }
  }

  // ---- logits + log_softmax ----
  float S[4];
#pragma unroll
  for (int o = 0; o < 4; ++o) {
    float s = 0.f;
#pragma unroll
    for (int m = 0; m < 16; ++m) {
      const int r = (m & 3) + 8 * (m >> 2) + 4 * half;
      s = fmaf(Wc[o * 1024 + r * 32 + col], G[m], s);
    }
    S[o] = s;
  }
#pragma unroll
  for (int off = 32; off >= 1; off >>= 1) {
    S[0] += __shfl_xor(S[0], off);
    S[1] += __shfl_xor(S[1], off);
    S[2] += __shfl_xor(S[2], off);
    S[3] += __shfl_xor(S[3], off);
  }
  if (l == 0) {
    const float lg0 = S[0] + bcv[0];
    const float lg1 = S[1] + bcv[1];
    const float lg2 = S[2] + bcv[2];
    const float lg3 = S[3] + bcv[3];
    const float mx = fmaxf(fmaxf(lg0, lg1), fmaxf(lg2, lg3));
    const float se = expf(lg0 - mx) + expf(lg1 - mx) +
                     expf(lg2 - mx) + expf(lg3 - mx);
    const float lse = mx + logf(se);
    *(float4*)&out[(size_t)b * 4] =
        make_float4(lg0 - lse, lg1 - lse, lg2 - lse, lg3 - lse);
  }
}

extern "C" void kernel_launch(void* const* d_in, const int* in_sizes, int n_in,
                              void* d_out, int out_size, void* d_ws, size_t ws_size,
                              hipStream_t stream)
{
  const float* x  = (const float*)d_in[0];
  const float* W  = (const float*)d_in[1];
  const float* Wc = (const float*)d_in[2];
  const float* bc = (const float*)d_in[3];
  float* out = (float*)d_out;
  (void)d_ws; (void)ws_size;

  const int nB = in_sizes[0] / (64 * 256);   // 4096
  const int blocks = (nB + 3) / 4;

  spd_fused<<<blocks, 256, 0, stream>>>(x, W, Wc, bc, out, nB);
}

// Round 14
// 55.316 us; speedup vs baseline: 1.6512x; 1.6512x over previous
//
#include <hip/hip_runtime.h>
#include <math.h>

// SPDNet fused, one wave per sample, no LDS, no scratch (R8 structure, NCH 9):
//  phase 1: Craw quadrants = sum_t x_t x_t^T via MFMA, x packed single-bf16,
//           lane = channel -> dwordx4 loads along t. 4-slot depth-3 software
//           pipeline (proven best of 5 structures tested R6-R13).
//  cov:     Cov = Craw/256 - mx mx^T (in-place on C-layout regs)
//  sandwich: Z = Cov*W ; Y = Z^T*W   (bf16 hi/lo rn-split, 3-product MFMA)
//  phase 2: log(Y) via degree-9 Chebyshev on [0.25,2.25] (p=1.25,q=1,r=-0.5)
//  epilogue: logits = <Wc_o, log(Y)> + bc -> log_softmax -> out.

typedef __attribute__((ext_vector_type(8))) short short8;   // bf16x8 frag
typedef __attribute__((ext_vector_type(16))) float f32x16;  // MFMA C/D

#define NCH 9

__device__ inline unsigned cvt_pk_bf16(float a, float b) {
  unsigned r;
  asm("v_cvt_pk_bf16_f32 %0, %1, %2" : "=v"(r) : "v"(a), "v"(b));
  return r;
}
__device__ inline void split_pair(float a, float b, unsigned& hp, unsigned& lp) {
  hp = cvt_pk_bf16(a, b);
  const float ha = __builtin_bit_cast(float, hp << 16);
  const float hb = __builtin_bit_cast(float, hp & 0xffff0000u);
  lp = cvt_pk_bf16(a - ha, b - hb);
}
// two float4 (8 consecutive k) -> single rn-bf16 frag
__device__ inline short8 pack8f(const float4& u, const float4& v) {
  union { unsigned u4[4]; short8 s; } H;
  H.u4[0] = cvt_pk_bf16(u.x, u.y);
  H.u4[1] = cvt_pk_bf16(u.z, u.w);
  H.u4[2] = cvt_pk_bf16(v.x, v.y);
  H.u4[3] = cvt_pk_bf16(v.z, v.w);
  return H.s;
}

// C-layout (lane: col=l&31, rows (m&3)+8*(m>>2)+4*(l>>5)) of matrix M ->
// frag pairs for two K=16 slices, hi/lo split. As A-operand == M^T (== M when
// M symmetric), as B-operand == M.
__device__ inline void c2frags(const float* c, short8& h0, short8& l0,
                               short8& h1, short8& l1) {
  unsigned ph[8], pl[8];
#pragma unroll
  for (int w = 0; w < 8; ++w) split_pair(c[2 * w], c[2 * w + 1], ph[w], pl[w]);
  union { unsigned u[4]; short8 s; } H0, L0, H1, L1;
  auto r = __builtin_amdgcn_permlane32_swap((int)ph[0], (int)ph[2], false, false);
  H0.u[0] = (unsigned)r[0]; H0.u[2] = (unsigned)r[1];
  r = __builtin_amdgcn_permlane32_swap((int)ph[1], (int)ph[3], false, false);
  H0.u[1] = (unsigned)r[0]; H0.u[3] = (unsigned)r[1];
  r = __builtin_amdgcn_permlane32_swap((int)ph[4], (int)ph[6], false, false);
  H1.u[0] = (unsigned)r[0]; H1.u[2] = (unsigned)r[1];
  r = __builtin_amdgcn_permlane32_swap((int)ph[5], (int)ph[7], false, false);
  H1.u[1] = (unsigned)r[0]; H1.u[3] = (unsigned)r[1];
  r = __builtin_amdgcn_permlane32_swap((int)pl[0], (int)pl[2], false, false);
  L0.u[0] = (unsigned)r[0]; L0.u[2] = (unsigned)r[1];
  r = __builtin_amdgcn_permlane32_swap((int)pl[1], (int)pl[3], false, false);
  L0.u[1] = (unsigned)r[0]; L0.u[3] = (unsigned)r[1];
  r = __builtin_amdgcn_permlane32_swap((int)pl[4], (int)pl[6], false, false);
  L1.u[0] = (unsigned)r[0]; L1.u[2] = (unsigned)r[1];
  r = __builtin_amdgcn_permlane32_swap((int)pl[5], (int)pl[7], false, false);
  L1.u[1] = (unsigned)r[0]; L1.u[3] = (unsigned)r[1];
  h0 = H0.s; l0 = L0.s; h1 = H1.s; l1 = L1.s;
}

__device__ inline f32x16 mfma_bf16(short8 a, short8 b, f32x16 c) {
  return __builtin_amdgcn_mfma_f32_32x32x16_bf16(a, b, c, 0, 0, 0);
}
__device__ inline f32x16 zero16() {
  f32x16 z;
#pragma unroll
  for (int i = 0; i < 16; ++i) z[i] = 0.f;
  return z;
}
// W B-frag for channel-slice cs (k = cs*16+8*half+j), hi/lo split
__device__ inline void loadWfrag(const float* __restrict__ W, int cs, int half,
                                 int col, short8& h, short8& l) {
  float wr[8];
#pragma unroll
  for (int j = 0; j < 8; ++j) wr[j] = W[(cs * 16 + 8 * half + j) * 32 + col];
  union { unsigned u4[4]; short8 s; } H, L;
#pragma unroll
  for (int w = 0; w < 4; ++w) split_pair(wr[2 * w], wr[2 * w + 1], H.u4[w], L.u4[w]);
  h = H.s; l = L.s;
}

__global__ __launch_bounds__(256) void spd_fused(
    const float* __restrict__ x, const float* __restrict__ W,
    const float* __restrict__ Wc, const float* __restrict__ bcv,
    float* __restrict__ out, int nB)
{
  const int wv = threadIdx.x >> 6;
  const int l  = threadIdx.x & 63;
  const int b  = blockIdx.x * 4 + wv;
  if (b >= nB) return;
  const int half = l >> 5, col = l & 31;

  // ---- phase 1: Craw quadrants, 3-deep load pipeline ----
  const float* xb = x + (size_t)b * (64 * 256);
  const float* r0 = xb + col * 256 + 8 * half;        // channel col
  const float* r1 = r0 + 32 * 256;                    // channel 32+col

  f32x16 C00 = zero16(), C01 = zero16(), C10 = zero16(), C11 = zero16();
  float macc0 = 0.f, macc1 = 0.f;

  float4 buf[4][8];

#define LOADTB(slot, tb)                                                   \
  {                                                                        \
    const float* pa = r0 + (tb) * 32;                                      \
    buf[slot][0] = *(const float4*)(pa);                                   \
    buf[slot][1] = *(const float4*)(pa + 4);                               \
    buf[slot][2] = *(const float4*)(pa + 16);                              \
    buf[slot][3] = *(const float4*)(pa + 20);                              \
    const float* pb = r1 + (tb) * 32;                                      \
    buf[slot][4] = *(const float4*)(pb);                                   \
    buf[slot][5] = *(const float4*)(pb + 4);                               \
    buf[slot][6] = *(const float4*)(pb + 16);                              \
    buf[slot][7] = *(const float4*)(pb + 20);                              \
  }

  LOADTB(0, 0) LOADTB(1, 1) LOADTB(2, 2)

#pragma unroll
  for (int tb = 0; tb < 8; ++tb) {
    if (tb + 3 < 8) LOADTB((tb + 3) & 3, tb + 3)
    const int s = tb & 3;
    const float4 a0 = buf[s][0], a1 = buf[s][1], a2 = buf[s][2], a3 = buf[s][3];
    const float4 b0 = buf[s][4], b1 = buf[s][5], b2 = buf[s][6], b3 = buf[s][7];

    macc0 += (a0.x + a0.y + a0.z + a0.w) + (a1.x + a1.y + a1.z + a1.w) +
             (a2.x + a2.y + a2.z + a2.w) + (a3.x + a3.y + a3.z + a3.w);
    macc1 += (b0.x + b0.y + b0.z + b0.w) + (b1.x + b1.y + b1.z + b1.w) +
             (b2.x + b2.y + b2.z + b2.w) + (b3.x + b3.y + b3.z + b3.w);

    const short8 A0 = pack8f(a0, a1), A1 = pack8f(a2, a3);
    const short8 B0 = pack8f(b0, b1), B1 = pack8f(b2, b3);

    C00 = mfma_bf16(A0, A0, C00); C00 = mfma_bf16(A1, A1, C00);
    C01 = mfma_bf16(A0, B0, C01); C01 = mfma_bf16(A1, B1, C01);
    C10 = mfma_bf16(B0, A0, C10); C10 = mfma_bf16(B1, A1, C10);
    C11 = mfma_bf16(B0, B0, C11); C11 = mfma_bf16(B1, B1, C11);
  }
#undef LOADTB

  // ---- means + correction: Cov = Craw/256 - mx mx^T (in-place) ----
  macc0 += __shfl_xor(macc0, 32);
  macc1 += __shfl_xor(macc1, 32);
  const float mx0 = macc0 * (1.f / 256.f);   // channel col
  const float mx1 = macc1 * (1.f / 256.f);   // channel 32+col
#pragma unroll
  for (int m = 0; m < 16; ++m) {
    const int r = (m & 3) + 8 * (m >> 2) + 4 * half;
    const float mr0 = __shfl(mx0, r);
    const float mr1 = __shfl(mx1, r);
    C00[m] = C00[m] * (1.f / 256.f) - mr0 * mx0;
    C01[m] = C01[m] * (1.f / 256.f) - mr0 * mx1;
    C10[m] = C10[m] * (1.f / 256.f) - mr1 * mx0;
    C11[m] = C11[m] * (1.f / 256.f) - mr1 * mx1;
  }

  // ---- eager quadrant->frag conversion (frees each accumulator asap) ----
  short8 f00h0, f00l0, f00h1, f00l1;   // A -> C00 (sym)
  {
    float t[16];
#pragma unroll
    for (int m = 0; m < 16; ++m) t[m] = C00[m];
    c2frags(t, f00h0, f00l0, f00h1, f00l1);
  }
  short8 f01h0, f01l0, f01h1, f01l1;   // A -> C01^T = C10
  {
    float t[16];
#pragma unroll
    for (int m = 0; m < 16; ++m) t[m] = C01[m];
    c2frags(t, f01h0, f01l0, f01h1, f01l1);
  }
  short8 f10h0, f10l0, f10h1, f10l1;   // A -> C10^T = C01
  {
    float t[16];
#pragma unroll
    for (int m = 0; m < 16; ++m) t[m] = C10[m];
    c2frags(t, f10h0, f10l0, f10h1, f10l1);
  }
  short8 f11h0, f11l0, f11h1, f11l1;   // A -> C11 (sym)
  {
    float t[16];
#pragma unroll
    for (int m = 0; m < 16; ++m) t[m] = C11[m];
    c2frags(t, f11h0, f11l0, f11h1, f11l1);
  }

  // ---- sandwich: Z = Cov*W (Z0 rows 0-31, Z1 rows 32-63) ----
  f32x16 Z0 = zero16(), Z1 = zero16();
  {
    short8 wh0, wl0, wh1, wl1;
    loadWfrag(W, 0, half, col, wh0, wl0);
    loadWfrag(W, 1, half, col, wh1, wl1);
    Z0 = mfma_bf16(f00h0, wh0, Z0); Z0 = mfma_bf16(f00h0, wl0, Z0); Z0 = mfma_bf16(f00l0, wh0, Z0);
    Z0 = mfma_bf16(f00h1, wh1, Z0); Z0 = mfma_bf16(f00h1, wl1, Z0); Z0 = mfma_bf16(f00l1, wh1, Z0);
    Z1 = mfma_bf16(f01h0, wh0, Z1); Z1 = mfma_bf16(f01h0, wl0, Z1); Z1 = mfma_bf16(f01l0, wh0, Z1);
    Z1 = mfma_bf16(f01h1, wh1, Z1); Z1 = mfma_bf16(f01h1, wl1, Z1); Z1 = mfma_bf16(f01l1, wh1, Z1);
  }
  {
    short8 wh2, wl2, wh3, wl3;
    loadWfrag(W, 2, half, col, wh2, wl2);
    loadWfrag(W, 3, half, col, wh3, wl3);
    Z0 = mfma_bf16(f10h0, wh2, Z0); Z0 = mfma_bf16(f10h0, wl2, Z0); Z0 = mfma_bf16(f10l0, wh2, Z0);
    Z0 = mfma_bf16(f10h1, wh3, Z0); Z0 = mfma_bf16(f10h1, wl3, Z0); Z0 = mfma_bf16(f10l1, wh3, Z0);
    Z1 = mfma_bf16(f11h0, wh2, Z1); Z1 = mfma_bf16(f11h0, wl2, Z1); Z1 = mfma_bf16(f11l0, wh2, Z1);
    Z1 = mfma_bf16(f11h1, wh3, Z1); Z1 = mfma_bf16(f11h1, wl3, Z1); Z1 = mfma_bf16(f11l1, wh3, Z1);
  }

  // ---- Y = Z^T * W (K = 64 channel rows of Z) ----
  f32x16 Ya = zero16();
  {
    short8 zh0, zl0, zh1, zl1;     // A -> Z0^T
    {
      float t[16];
#pragma unroll
      for (int m = 0; m < 16; ++m) t[m] = Z0[m];
      c2frags(t, zh0, zl0, zh1, zl1);
    }
    short8 wh0, wl0, wh1, wl1;
    loadWfrag(W, 0, half, col, wh0, wl0);
    loadWfrag(W, 1, half, col, wh1, wl1);
    Ya = mfma_bf16(zh0, wh0, Ya); Ya = mfma_bf16(zh0, wl0, Ya); Ya = mfma_bf16(zl0, wh0, Ya);
    Ya = mfma_bf16(zh1, wh1, Ya); Ya = mfma_bf16(zh1, wl1, Ya); Ya = mfma_bf16(zl1, wh1, Ya);
  }
  {
    short8 zh0, zl0, zh1, zl1;     // A -> Z1^T
    {
      float t[16];
#pragma unroll
      for (int m = 0; m < 16; ++m) t[m] = Z1[m];
      c2frags(t, zh0, zl0, zh1, zl1);
    }
    short8 wh2, wl2, wh3, wl3;
    loadWfrag(W, 2, half, col, wh2, wl2);
    loadWfrag(W, 3, half, col, wh3, wl3);
    Ya = mfma_bf16(zh0, wh2, Ya); Ya = mfma_bf16(zh0, wl2, Ya); Ya = mfma_bf16(zl0, wh2, Ya);
    Ya = mfma_bf16(zh1, wh3, Ya); Ya = mfma_bf16(zh1, wl3, Ya); Ya = mfma_bf16(zl1, wh3, Ya);
  }

  // ---- phase 2: Chebyshev log on [0.25, 2.25]: p=1.25, q=1, r=-0.5, c0=0 ----
  float Tc[16], Tp[16], G[16];
#pragma unroll
  for (int m = 0; m < 16; ++m) {
    const int r = (m & 3) + 8 * (m >> 2) + 4 * half;
    const float dg = (r == col) ? 1.f : 0.f;
    const float yn = Ya[m] - 1.25f * dg;      // u = (Y - p I)/q, q=1
    Tc[m] = yn; Tp[m] = dg;
    G[m] = yn;                                 // c1 = -2r = 1, c0 = 0
  }
  short8 ah0, al0, ah1, al1;
  c2frags(Tc, ah0, al0, ah1, al1);             // A-frags of symmetric Yhat

  constexpr float CK[NCH + 1] = {
      0.f, 1.f, -0.25f, 0.083333336f, -0.03125f, 0.0125f, -0.0052083335f,
      0.0022321427f, -0.0009765625f, 0.00043402778f};
#pragma unroll
  for (int k = 2; k <= NCH; ++k) {
    short8 bh0, bl0, bh1, bl1;
    c2frags(Tc, bh0, bl0, bh1, bl1);
    f32x16 P1 = zero16(), P2 = zero16();
    P1 = mfma_bf16(ah0, bh0, P1); P1 = mfma_bf16(ah0, bl0, P1); P1 = mfma_bf16(al0, bh0, P1);
    P2 = mfma_bf16(ah1, bh1, P2); P2 = mfma_bf16(ah1, bl1, P2); P2 = mfma_bf16(al1, bh1, P2);
    const float ck = CK[k];
#pragma unroll
    for (int m = 0; m < 16; ++m) {
      const float tn = 2.f * (P1[m] + P2[m]) - Tp[m];
      Tp[m] = Tc[m]; Tc[m] = tn;
      G[m] = fmaf(ck, tn, G[m]);
    }
  }

  // ---- logits + log_softmax ----
  float S[4];
#pragma unroll
  for (int o = 0; o < 4; ++o) {
    float s = 0.f;
#pragma unroll
    for (int m = 0; m < 16; ++m) {
      const int r = (m & 3) + 8 * (m >> 2) + 4 * half;
      s = fmaf(Wc[o * 1024 + r * 32 + col], G[m], s);
    }
    S[o] = s;
  }
#pragma unroll
  for (int off = 32; off >= 1; off >>= 1) {
    S[0] += __shfl_xor(S[0], off);
    S[1] += __shfl_xor(S[1], off);
    S[2] += __shfl_xor(S[2], off);
    S[3] += __shfl_xor(S[3], off);
  }
  if (l == 0) {
    const float lg0 = S[0] + bcv[0];
    const float lg1 = S[1] + bcv[1];
    const float lg2 = S[2] + bcv[2];
    const float lg3 = S[3] + bcv[3];
    const float mx = fmaxf(fmaxf(lg0, lg1), fmaxf(lg2, lg3));
    const float se = expf(lg0 - mx) + expf(lg1 - mx) +
                     expf(lg2 - mx) + expf(lg3 - mx);
    const float lse = mx + logf(se);
    *(float4*)&out[(size_t)b * 4] =
        make_float4(lg0 - lse, lg1 - lse, lg2 - lse, lg3 - lse);
  }
}

extern "C" void kernel_launch(void* const* d_in, const int* in_sizes, int n_in,
                              void* d_out, int out_size, void* d_ws, size_t ws_size,
                              hipStream_t stream)
{
  const float* x  = (const float*)d_in[0];
  const float* W  = (const float*)d_in[1];
  const float* Wc = (const float*)d_in[2];
  const float* bc = (const float*)d_in[3];
  float* out = (float*)d_out;
  (void)d_ws; (void)ws_size;

  const int nB = in_sizes[0] / (64 * 256);   // 4096
  const int blocks = (nB + 3) / 4;

  spd_fused<<<blocks, 256, 0, stream>>>(x, W, Wc, bc, out, nB);
}